// Round 1
// baseline (332.281 us; speedup 1.0000x reference)
//
#include <hip/hip_runtime.h>

typedef short s16x8 __attribute__((ext_vector_type(8)));
typedef float f32x4 __attribute__((ext_vector_type(4)));

__device__ inline unsigned short f2bf(float f){
    union{float f;unsigned u;} v{f};
    unsigned r = v.u + 0x7fff + ((v.u>>16)&1);
    return (unsigned short)(r>>16);
}
__device__ inline float bf2f(unsigned short h){
    union{unsigned u;float f;} v{(unsigned)h<<16};
    return v.f;
}

// ---------------- cast fp32 -> bf16, vectorized x4 ----------------
__global__ void cast_f32_bf16(const float* __restrict__ src, unsigned short* __restrict__ dst, int n4){
    int i = blockIdx.x*blockDim.x + threadIdx.x;
    if(i < n4){
        float4 f = ((const float4*)src)[i];
        ushort4 o;
        o.x = f2bf(f.x); o.y = f2bf(f.y); o.z = f2bf(f.z); o.w = f2bf(f.w);
        ((ushort4*)dst)[i] = o;
    }
}

// ---------------- C[M,N] = A[M,K] * B[N,K]^T + bias, bf16 in, 128x128 tile ----------------
// 4 waves, each computes 64x64 via 4x4 grid of 16x16x32 MFMA tiles.
template<int BF16OUT>
__launch_bounds__(256,2)
__global__ void gemm_bt(const unsigned short* __restrict__ A, const unsigned short* __restrict__ B,
                        const float* __restrict__ bias, void* __restrict__ Cv,
                        int M, int N, int K){
    const int LDT = 40; // +8 pad: frag-read banks 2-way (free)
    __shared__ __attribute__((aligned(16))) unsigned short sA[128*40];
    __shared__ __attribute__((aligned(16))) unsigned short sB[128*40];
    int t = threadIdx.x;
    int bm = blockIdx.y, bn = blockIdx.x;
    int lane = t & 63, wave = t >> 6;
    int quad = lane >> 4, l15 = lane & 15;
    int wm = wave >> 1, wn = wave & 1;

    int srow = t >> 2;       // 0..63
    int scol = (t & 3) * 8;  // 0,8,16,24
    const unsigned short* Ab = A + (size_t)(bm*128 + srow)*K + scol;
    const unsigned short* Bb = B + (size_t)(bn*128 + srow)*K + scol;

    f32x4 acc[4][4];
    #pragma unroll
    for(int i=0;i<4;i++)
        #pragma unroll
        for(int j=0;j<4;j++) acc[i][j] = (f32x4){0.f,0.f,0.f,0.f};

    for(int k0=0; k0<K; k0+=32){
        uint4 a0 = *(const uint4*)(Ab + k0);
        uint4 a1 = *(const uint4*)(Ab + (size_t)64*K + k0);
        uint4 b0 = *(const uint4*)(Bb + k0);
        uint4 b1 = *(const uint4*)(Bb + (size_t)64*K + k0);
        *(uint4*)&sA[srow*LDT + scol]      = a0;
        *(uint4*)&sA[(srow+64)*LDT + scol] = a1;
        *(uint4*)&sB[srow*LDT + scol]      = b0;
        *(uint4*)&sB[(srow+64)*LDT + scol] = b1;
        __syncthreads();
        s16x8 af[4], bfr[4];
        #pragma unroll
        for(int i=0;i<4;i++) af[i]  = *(const s16x8*)&sA[(wm*64 + i*16 + l15)*LDT + quad*8];
        #pragma unroll
        for(int j=0;j<4;j++) bfr[j] = *(const s16x8*)&sB[(wn*64 + j*16 + l15)*LDT + quad*8];
        #pragma unroll
        for(int i=0;i<4;i++)
            #pragma unroll
            for(int j=0;j<4;j++)
                acc[i][j] = __builtin_amdgcn_mfma_f32_16x16x32_bf16(af[i], bfr[j], acc[i][j], 0,0,0);
        __syncthreads();
    }

    int row0 = bm*128 + wm*64;
    int col0 = bn*128 + wn*64;
    #pragma unroll
    for(int j=0;j<4;j++){
        int col = col0 + j*16 + l15;
        float bv = bias[col];
        #pragma unroll
        for(int i=0;i<4;i++){
            int rbase = row0 + i*16 + quad*4;
            #pragma unroll
            for(int r=0;r<4;r++){
                float v = acc[i][j][r] + bv;
                if(BF16OUT) ((unsigned short*)Cv)[(size_t)(rbase+r)*N + col] = f2bf(v);
                else        ((float*)Cv)[(size_t)(rbase+r)*N + col] = v;
            }
        }
    }
}

// ---------------- S[head][d][e] += sum_m Q(m,d)*K(m,e) over a 256-token chunk ----------------
__global__ void attn_scores(const unsigned short* __restrict__ qkv, float* __restrict__ S){
    __shared__ __attribute__((aligned(16))) unsigned short sQ[2048];
    __shared__ __attribute__((aligned(16))) unsigned short sK[2048];
    int t = threadIdx.x;
    int head = blockIdx.y;   // b*8+h
    int chunk = blockIdx.x;  // 16 chunks x 256 tokens
    int rbase = head*512;    // b*4096 + h*512 == (8b+h)*512
    float acc[16];
    #pragma unroll
    for(int i=0;i<16;i++) acc[i]=0.f;
    int d0 = (t&15)*4, e0 = (t>>4)*4;
    for(int tile=0; tile<8; tile++){
        int r  = rbase + chunk*32 + tile*4 + (t>>6);
        int ch = (t&63)*8;
        *(uint4*)&sQ[t*8] = *(const uint4*)&qkv[(size_t)r*1536 + ch];
        *(uint4*)&sK[t*8] = *(const uint4*)&qkv[(size_t)r*1536 + 512 + ch];
        __syncthreads();
        #pragma unroll 8
        for(int tok=0; tok<32; tok++){
            ushort4 qu = *(const ushort4*)&sQ[tok*64 + d0];
            ushort4 ku = *(const ushort4*)&sK[tok*64 + e0];
            float q0=bf2f(qu.x), q1=bf2f(qu.y), q2=bf2f(qu.z), q3=bf2f(qu.w);
            float k0=bf2f(ku.x), k1=bf2f(ku.y), k2=bf2f(ku.z), k3=bf2f(ku.w);
            acc[0]+=q0*k0; acc[1]+=q0*k1; acc[2]+=q0*k2; acc[3]+=q0*k3;
            acc[4]+=q1*k0; acc[5]+=q1*k1; acc[6]+=q1*k2; acc[7]+=q1*k3;
            acc[8]+=q2*k0; acc[9]+=q2*k1; acc[10]+=q2*k2; acc[11]+=q2*k3;
            acc[12]+=q3*k0; acc[13]+=q3*k1; acc[14]+=q3*k2; acc[15]+=q3*k3;
        }
        __syncthreads();
    }
    float* Sh = S + head*4096;
    #pragma unroll
    for(int i=0;i<4;i++)
        #pragma unroll
        for(int j=0;j<4;j++)
            atomicAdd(&Sh[(d0+i)*64 + e0 + j], acc[i*4+j]);
}

// ---------------- softmax over e of S*0.125, write bf16 weights ----------------
__global__ void softmax64(const float* __restrict__ S, unsigned short* __restrict__ W){
    int head = blockIdx.x;
    int d = threadIdx.x; // 64 threads
    const float* row = S + head*4096 + (size_t)d*64;
    float vals[64];
    float m = -1e30f;
    #pragma unroll
    for(int e=0;e<64;e++){ float v = row[e]*0.125f; vals[e]=v; m = fmaxf(m, v); }
    float s = 0.f;
    #pragma unroll
    for(int e=0;e<64;e++){ float x = __expf(vals[e]-m); vals[e]=x; s += x; }
    float inv = 1.f/s;
    unsigned short* wr = W + head*4096 + (size_t)d*64;
    #pragma unroll
    for(int e=0;e<64;e++) wr[e] = f2bf(vals[e]*inv);
}

// ---------------- attn[b*4096+m, h*64+d] = sum_e V(m,e)*W(d,e), MFMA, K=64 ----------------
__launch_bounds__(256,2)
__global__ void attn_pv(const unsigned short* __restrict__ qkv, const unsigned short* __restrict__ W,
                        unsigned short* __restrict__ attn){
    const int LV = 72; // pad: 2-way bank on frag reads, keeps 16B alignment (144B rows)
    __shared__ __attribute__((aligned(16))) unsigned short sV[128*72];
    __shared__ __attribute__((aligned(16))) unsigned short sW[64*72];
    int t = threadIdx.x;
    int head = blockIdx.y, chunk = blockIdx.x; // 32 chunks x 128 tokens
    int rbase = head*512;
    #pragma unroll
    for(int it=0; it<4; it++){
        int i = it*2048 + t*8;
        int tok = i>>6, e = i&63;
        int qrow = i>>9, ch = i&511;
        *(uint4*)&sV[tok*LV + e] = *(const uint4*)&qkv[(size_t)(rbase + chunk*16 + qrow)*1536 + 1024 + ch];
    }
    #pragma unroll
    for(int it=0; it<2; it++){
        int i = it*2048 + t*8;
        int dd = i>>6, e = i&63;
        *(uint4*)&sW[dd*LV + e] = *(const uint4*)&W[head*4096 + i];
    }
    __syncthreads();
    int lane = t&63, w = t>>6, quad = lane>>4, l15 = lane&15;
    f32x4 acc[2][4];
    #pragma unroll
    for(int i=0;i<2;i++)
        #pragma unroll
        for(int j=0;j<4;j++) acc[i][j] = (f32x4){0.f,0.f,0.f,0.f};
    #pragma unroll
    for(int ks=0; ks<2; ks++){
        int k0 = ks*32;
        s16x8 af[2], bfr[4];
        #pragma unroll
        for(int mt=0;mt<2;mt++) af[mt]  = *(const s16x8*)&sV[(w*32+mt*16+l15)*LV + k0 + quad*8];
        #pragma unroll
        for(int nt=0;nt<4;nt++) bfr[nt] = *(const s16x8*)&sW[(nt*16+l15)*LV + k0 + quad*8];
        #pragma unroll
        for(int mt=0;mt<2;mt++)
            #pragma unroll
            for(int nt=0;nt<4;nt++)
                acc[mt][nt] = __builtin_amdgcn_mfma_f32_16x16x32_bf16(af[mt], bfr[nt], acc[mt][nt],0,0,0);
    }
    int b = head>>3, h = head&7;
    #pragma unroll
    for(int mt=0;mt<2;mt++){
        int mg = chunk*128 + w*32 + mt*16 + quad*4;
        #pragma unroll
        for(int nt=0;nt<4;nt++){
            int d = nt*16 + l15;
            #pragma unroll
            for(int r=0;r<4;r++){
                attn[(size_t)(b*4096 + mg + r)*512 + h*64 + d] = f2bf(acc[mt][nt][r]);
            }
        }
    }
}

extern "C" void kernel_launch(void* const* d_in, const int* in_sizes, int n_in,
                              void* d_out, int out_size, void* d_ws, size_t ws_size,
                              hipStream_t stream){
    const float* x      = (const float*)d_in[0];
    const float* wqkv_w = (const float*)d_in[1];
    const float* wqkv_b = (const float*)d_in[2];
    const float* wp_w   = (const float*)d_in[3];
    const float* wp_b   = (const float*)d_in[4];

    char* ws = (char*)d_ws;
    unsigned short* xbf    = (unsigned short*)(ws);                 // 32 MB
    unsigned short* wqkvbf = (unsigned short*)(ws + 33554432);      // 1.5 MB
    unsigned short* wpbf   = (unsigned short*)(ws + 35127296);      // 0.5 MB
    unsigned short* qkvbf  = (unsigned short*)(ws + 35651584);      // 96 MB
    float*          Sbuf   = (float*)(ws + 136314880);              // 1 MB
    unsigned short* Wsm    = (unsigned short*)(ws + 137363456);     // 0.5 MB
    unsigned short* attnbf = (unsigned short*)(ws + 137887744);     // 32 MB  (total ~171.5 MB)

    // casts
    cast_f32_bf16<<<16384,256,0,stream>>>(x,      xbf,    16777216/4);
    cast_f32_bf16<<<768,  256,0,stream>>>(wqkv_w, wqkvbf, 786432/4);
    cast_f32_bf16<<<256,  256,0,stream>>>(wp_w,   wpbf,   262144/4);

    // qkv = x @ wqkv^T + b   (M=32768, N=1536, K=512)
    gemm_bt<1><<<dim3(12,256),256,0,stream>>>(xbf, wqkvbf, wqkv_b, (void*)qkvbf, 32768,1536,512);

    // scores (atomically accumulated) -> softmax -> weights
    hipMemsetAsync(Sbuf, 0, 64*64*64*sizeof(float), stream);
    attn_scores<<<dim3(16,64),256,0,stream>>>(qkvbf, Sbuf);
    softmax64<<<64,64,0,stream>>>(Sbuf, Wsm);

    // y = W @ V^T  -> attn (b,n,c) layout, bf16
    attn_pv<<<dim3(32,64),256,0,stream>>>(qkvbf, Wsm, attnbf);

    // out = attn @ wp^T + b  (M=32768, N=512, K=512), fp32 out
    gemm_bt<0><<<dim3(4,256),256,0,stream>>>(attnbf, wpbf, wp_b, d_out, 32768,512,512);
}

// Round 2
// 271.151 us; speedup vs baseline: 1.2254x; 1.2254x over previous
//
#include <hip/hip_runtime.h>

typedef short s16x8 __attribute__((ext_vector_type(8)));
typedef float f32x4 __attribute__((ext_vector_type(4)));
typedef unsigned short us;

__device__ inline us f2bf(float f){
    union{float f;unsigned u;} v{f};
    unsigned r = v.u + 0x7fff + ((v.u>>16)&1);
    return (us)(r>>16);
}
__device__ inline float bf2f(us h){
    union{unsigned u;float f;} v{(unsigned)h<<16};
    return v.f;
}

__device__ __forceinline__ void glds16(const us* g, us* l){
    __builtin_amdgcn_global_load_lds(
        (const __attribute__((address_space(1))) unsigned int*)(g),
        (__attribute__((address_space(3))) unsigned int*)(l), 16, 0, 0);
}

// ---------------- cast fp32 -> bf16, vectorized x4 ----------------
__global__ void cast_f32_bf16(const float* __restrict__ src, us* __restrict__ dst, int n4){
    int i = blockIdx.x*blockDim.x + threadIdx.x;
    if(i < n4){
        float4 f = ((const float4*)src)[i];
        ushort4 o;
        o.x = f2bf(f.x); o.y = f2bf(f.y); o.z = f2bf(f.z); o.w = f2bf(f.w);
        ((ushort4*)dst)[i] = o;
    }
}

// ---------------- C[M,N] = A[M,K]*B[N,K]^T + bias; m97 structure (glds width-16) ----
// 128x128 tile, BK=32, unpadded LDS [row][32] (glds constraint). 4 waves, 4x4 frags.
template<int BF16OUT>
__launch_bounds__(256,2)
__global__ void gemm_bt(const us* __restrict__ A, const us* __restrict__ B,
                        const float* __restrict__ bias, void* __restrict__ Cv,
                        int M, int N, int K){
    __shared__ __attribute__((aligned(16))) us sA[128*32];
    __shared__ __attribute__((aligned(16))) us sB[128*32];
    int t = threadIdx.x;
    int bm = blockIdx.y, bn = blockIdx.x;
    int lane = t & 63, wave = t >> 6;
    int quad = lane >> 4, l15 = lane & 15;
    int wm = wave >> 1, wn = wave & 1;

    // staging: wave stages rows [wave*32, wave*32+32) of A and B tiles.
    // lane i -> row +(i>>2), col (i&3)*8 ; lds slot = base + i*8 elems (glds lane x16B)
    int srow = wave*32 + (lane>>2);
    int scol = (lane&3)*8;
    const us* Ag = A + (size_t)(bm*128 + srow)*K + scol;
    const us* Bg = B + (size_t)(bn*128 + srow)*K + scol;
    us* sAw = &sA[(wave*32)*32];
    us* sBw = &sB[(wave*32)*32];

    f32x4 acc[4][4];
    #pragma unroll
    for(int i=0;i<4;i++)
        #pragma unroll
        for(int j=0;j<4;j++) acc[i][j] = (f32x4){0.f,0.f,0.f,0.f};

    for(int k0=0; k0<K; k0+=32){
        glds16(Ag + k0,                sAw);
        glds16(Ag + (size_t)16*K + k0, sAw + 16*32);
        glds16(Bg + k0,                sBw);
        glds16(Bg + (size_t)16*K + k0, sBw + 16*32);
        __syncthreads();
        s16x8 af[4], bfr[4];
        #pragma unroll
        for(int i=0;i<4;i++) af[i]  = *(const s16x8*)&sA[(wm*64 + i*16 + l15)*32 + quad*8];
        #pragma unroll
        for(int j=0;j<4;j++) bfr[j] = *(const s16x8*)&sB[(wn*64 + j*16 + l15)*32 + quad*8];
        #pragma unroll
        for(int i=0;i<4;i++)
            #pragma unroll
            for(int j=0;j<4;j++)
                acc[i][j] = __builtin_amdgcn_mfma_f32_16x16x32_bf16(af[i], bfr[j], acc[i][j], 0,0,0);
        __syncthreads();
    }

    int row0 = bm*128 + wm*64;
    int col0 = bn*128 + wn*64;
    #pragma unroll
    for(int j=0;j<4;j++){
        int col = col0 + j*16 + l15;
        float bv = bias[col];
        #pragma unroll
        for(int i=0;i<4;i++){
            int rbase = row0 + i*16 + quad*4;
            #pragma unroll
            for(int r=0;r<4;r++){
                float v = acc[i][j][r] + bv;
                if(BF16OUT) ((us*)Cv)[(size_t)(rbase+r)*N + col] = f2bf(v);
                else        ((float*)Cv)[(size_t)(rbase+r)*N + col] = v;
            }
        }
    }
}

// ---- scores via MFMA: Spart[kb][head][d][e] = sum over 512 tokens Q(m,d)K(m,e) ----
// Q,K staged TRANSPOSED (d-major, tok contiguous) with XOR-16B-block swizzle.
__launch_bounds__(256,2)
__global__ void attn_scores_mfma(const us* __restrict__ qkv, float* __restrict__ Sp){
    // element index for (d, tok): d*64 + ((tok>>3) ^ (d>>3))*8 + (tok&7)
    __shared__ __attribute__((aligned(16))) us sQt[64*64];
    __shared__ __attribute__((aligned(16))) us sKt[64*64];
    int t = threadIdx.x;
    int kb = blockIdx.x, head = blockIdx.y;
    int lane = t & 63, w = t >> 6;
    int quad = lane >> 4, l15 = lane & 15;

    f32x4 acc[4];
    #pragma unroll
    for(int j=0;j<4;j++) acc[j] = (f32x4){0.f,0.f,0.f,0.f};

    for(int chunk=0; chunk<8; chunk++){
        int r0 = head*512 + kb*64 + chunk*8;  // 8 qkv rows = 64 tokens
        #pragma unroll
        for(int it=0; it<2; it++){
            int i = it*256 + t;
            int row8 = i>>6, l = i&63;
            int d0 = (l&7)*8;
            int off = ((row8 ^ (l&7))<<3) | (l>>3); // swizzled blk*8 + tokin
            const us* gq = qkv + (size_t)(r0+row8)*1536 + l*8;
            union{uint4 v; us s[8];} q, k;
            q.v = *(const uint4*)gq;
            k.v = *(const uint4*)(gq + 512);
            #pragma unroll
            for(int j=0;j<8;j++){
                sQt[(d0+j)*64 + off] = q.s[j];
                sKt[(d0+j)*64 + off] = k.s[j];
            }
        }
        __syncthreads();
        #pragma unroll
        for(int ks=0; ks<2; ks++){
            int d = w*16 + l15;
            int tb = ks*4 + quad;
            s16x8 af = *(const s16x8*)&sQt[d*64 + ((tb ^ (d>>3))<<3)];
            #pragma unroll
            for(int jt=0; jt<4; jt++){
                int e = jt*16 + l15;
                s16x8 bf = *(const s16x8*)&sKt[e*64 + ((tb ^ (e>>3))<<3)];
                acc[jt] = __builtin_amdgcn_mfma_f32_16x16x32_bf16(af, bf, acc[jt], 0,0,0);
            }
        }
        __syncthreads();
    }

    float* S = Sp + (size_t)(kb*64 + head)*4096;
    #pragma unroll
    for(int jt=0; jt<4; jt++){
        int e = jt*16 + l15;
        #pragma unroll
        for(int r=0; r<4; r++){
            int d = w*16 + quad*4 + r;
            S[d*64 + e] = acc[jt][r];
        }
    }
}

// ---- sum 8 partials, softmax over e (scale 1/8), write bf16 weights W[head][d][e] ----
__global__ void softmax_fuse(const float* __restrict__ Sp, us* __restrict__ W){
    int head = blockIdx.x;
    int t = threadIdx.x;           // 256
    int d = t>>2, eg = (t&3)*16;
    float v[16];
    #pragma unroll
    for(int e=0;e<16;e++) v[e]=0.f;
    for(int kb=0; kb<8; kb++){
        const float* p = Sp + (size_t)(kb*64 + head)*4096 + d*64 + eg;
        #pragma unroll
        for(int e4=0;e4<4;e4++){
            float4 f = ((const float4*)p)[e4];
            v[e4*4+0]+=f.x; v[e4*4+1]+=f.y; v[e4*4+2]+=f.z; v[e4*4+3]+=f.w;
        }
    }
    float m = -1e30f;
    #pragma unroll
    for(int e=0;e<16;e++){ v[e] *= 0.125f; m = fmaxf(m, v[e]); }
    m = fmaxf(m, __shfl_xor(m, 1));
    m = fmaxf(m, __shfl_xor(m, 2));
    float s = 0.f;
    #pragma unroll
    for(int e=0;e<16;e++){ v[e] = __expf(v[e]-m); s += v[e]; }
    s += __shfl_xor(s, 1);
    s += __shfl_xor(s, 2);
    float inv = 1.f/s;
    union{uint4 u[2]; us h[16];} o;
    #pragma unroll
    for(int e=0;e<16;e++) o.h[e] = f2bf(v[e]*inv);
    uint4* wp = (uint4*)(W + (size_t)head*4096 + d*64 + eg);
    wp[0] = o.u[0]; wp[1] = o.u[1];
}

// ---------------- attn[b*4096+m, h*64+d] = sum_e V(m,e)*W(d,e), MFMA, K=64 ----------------
__launch_bounds__(256,2)
__global__ void attn_pv(const us* __restrict__ qkv, const us* __restrict__ W,
                        us* __restrict__ attn){
    const int LV = 72;
    __shared__ __attribute__((aligned(16))) us sV[128*72];
    __shared__ __attribute__((aligned(16))) us sW[64*72];
    int t = threadIdx.x;
    int head = blockIdx.y, chunk = blockIdx.x; // 32 chunks x 128 tokens
    int rbase = head*512;
    #pragma unroll
    for(int it=0; it<4; it++){
        int i = it*2048 + t*8;
        int tok = i>>6, e = i&63;
        int qrow = i>>9, ch = i&511;
        *(uint4*)&sV[tok*LV + e] = *(const uint4*)&qkv[(size_t)(rbase + chunk*16 + qrow)*1536 + 1024 + ch];
    }
    #pragma unroll
    for(int it=0; it<2; it++){
        int i = it*2048 + t*8;
        int dd = i>>6, e = i&63;
        *(uint4*)&sW[dd*LV + e] = *(const uint4*)&W[head*4096 + i];
    }
    __syncthreads();
    int lane = t&63, w = t>>6, quad = lane>>4, l15 = lane&15;
    f32x4 acc[2][4];
    #pragma unroll
    for(int i=0;i<2;i++)
        #pragma unroll
        for(int j=0;j<4;j++) acc[i][j] = (f32x4){0.f,0.f,0.f,0.f};
    #pragma unroll
    for(int ks=0; ks<2; ks++){
        int k0 = ks*32;
        s16x8 af[2], bfr[4];
        #pragma unroll
        for(int mt=0;mt<2;mt++) af[mt]  = *(const s16x8*)&sV[(w*32+mt*16+l15)*LV + k0 + quad*8];
        #pragma unroll
        for(int nt=0;nt<4;nt++) bfr[nt] = *(const s16x8*)&sW[(nt*16+l15)*LV + k0 + quad*8];
        #pragma unroll
        for(int mt=0;mt<2;mt++)
            #pragma unroll
            for(int nt=0;nt<4;nt++)
                acc[mt][nt] = __builtin_amdgcn_mfma_f32_16x16x32_bf16(af[mt], bfr[nt], acc[mt][nt],0,0,0);
    }
    int b = head>>3, h = head&7;
    #pragma unroll
    for(int mt=0;mt<2;mt++){
        int mg = chunk*128 + w*32 + mt*16 + quad*4;
        #pragma unroll
        for(int nt=0;nt<4;nt++){
            int d = nt*16 + l15;
            #pragma unroll
            for(int r=0;r<4;r++){
                attn[(size_t)(b*4096 + mg + r)*512 + h*64 + d] = f2bf(acc[mt][nt][r]);
            }
        }
    }
}

extern "C" void kernel_launch(void* const* d_in, const int* in_sizes, int n_in,
                              void* d_out, int out_size, void* d_ws, size_t ws_size,
                              hipStream_t stream){
    const float* x      = (const float*)d_in[0];
    const float* wqkv_w = (const float*)d_in[1];
    const float* wqkv_b = (const float*)d_in[2];
    const float* wp_w   = (const float*)d_in[3];
    const float* wp_b   = (const float*)d_in[4];

    char* ws = (char*)d_ws;
    us*    qkvbf  = (us*)(ws);                    // 96 MB
    us*    xbf    = (us*)(ws + 100663296);        // 32 MB (reused as attnbf later)
    us*    attnbf = xbf;                          // liveness disjoint with xbf
    us*    wqkvbf = (us*)(ws + 134217728);        // 1.5 MB
    us*    wpbf   = (us*)(ws + 135790592);        // 0.5 MB
    float* Spart  = (float*)(ws + 136314880);     // 8 MB
    us*    Wsm    = (us*)(ws + 144703488);        // 0.5 MB  (total ~138.5 MB)

    cast_f32_bf16<<<16384,256,0,stream>>>(x,      xbf,    16777216/4);
    cast_f32_bf16<<<768,  256,0,stream>>>(wqkv_w, wqkvbf, 786432/4);
    cast_f32_bf16<<<256,  256,0,stream>>>(wp_w,   wpbf,   262144/4);

    // qkv = x @ wqkv^T + b   (M=32768, N=1536, K=512)
    gemm_bt<1><<<dim3(12,256),256,0,stream>>>(xbf, wqkvbf, wqkv_b, (void*)qkvbf, 32768,1536,512);

    // scores: 8-way K-split MFMA partials, then fused sum+softmax
    attn_scores_mfma<<<dim3(8,64),256,0,stream>>>(qkvbf, Spart);
    softmax_fuse<<<64,256,0,stream>>>(Spart, Wsm);

    // y = W @ V^T  -> attn (b,n,c) layout, bf16
    attn_pv<<<dim3(32,64),256,0,stream>>>(qkvbf, Wsm, attnbf);

    // out = attn @ wp^T + b  (M=32768, N=512, K=512), fp32 out
    gemm_bt<0><<<dim3(4,256),256,0,stream>>>(attnbf, wpbf, wp_b, d_out, 32768,512,512);
}